// Round 5
// baseline (237.970 us; speedup 1.0000x reference)
//
#include <hip/hip_runtime.h>
#include <math.h>

#define TT 4096
#define DM 1024
#define BB 4
#define BT (BB * TT)
#define SENT  0x7f7f7f7f
#define MAGIC 0x17C3A5E9
#define NBLK 1024

// ws layout (bytes):
//   Q        : u64[BT]   @ 0       (131072)  packed float2 (q0,q1)
//   K        : u64[BT]   @ 131072  (131072)  packed float2 (k0,k1)
//   idx      : int[BT]   @ 262144  (65536)
//   rep      : int[BT]   @ 327680  (65536)
//   rowdone  : int[BT]   @ 393216  (65536)
//   chunkdone: int[512]  @ 458752  (2048)    stamp per 32-row chunk
//   blkdone  : int[1024] @ 460800  (4096)    stamp per block (argmax done)
//   gen      : int       @ 464896  (4)       generation word (bumped at end)

__device__ __forceinline__ float dot4(const float4 a, const float4 b) {
    return a.x * b.x + a.y * b.y + a.z * b.z + a.w * b.w;
}
__device__ __forceinline__ int aload(const int* p) {
    return __hip_atomic_load((int*)p, __ATOMIC_RELAXED, __HIP_MEMORY_SCOPE_AGENT);
}
__device__ __forceinline__ void astore(int* p, int v) {
    __hip_atomic_store(p, v, __ATOMIC_RELAXED, __HIP_MEMORY_SCOPE_AGENT);
}
__device__ __forceinline__ void astore64(unsigned long long* p, unsigned long long v) {
    __hip_atomic_store(p, v, __ATOMIC_RELAXED, __HIP_MEMORY_SCOPE_AGENT);
}
__device__ __forceinline__ unsigned long long packf2(float a, float b) {
    union { float2 f; unsigned long long u; } cv;
    cv.f = make_float2(a, b);
    return cv.u;
}
__device__ __forceinline__ void spin_eq(const int* p, int v) {
    int it = 0;
    while (__hip_atomic_load((int*)p, __ATOMIC_RELAXED, __HIP_MEMORY_SCOPE_AGENT) != v) {
        __builtin_amdgcn_s_sleep(8);
        if (++it > (1 << 21)) break;   // ~0.5s cap: fail visibly, never hang
    }
}

// ============================================================================
// Single-dispatch dataflow kernel. 1024 blocks x 256. No grid barriers.
// Cross-block data via agent-scope atomics (coherent point), flags via stamps.
// ============================================================================
__global__ __launch_bounds__(256, 4) void mega_kernel(
    const float* __restrict__ x, const float* __restrict__ wq,
    const float* __restrict__ wk, const float* __restrict__ wv,
    unsigned long long* __restrict__ Qu, unsigned long long* __restrict__ Ku,
    int* __restrict__ idx, int* __restrict__ rep, int* __restrict__ rowdone,
    int* __restrict__ chunkdone, int* __restrict__ blkdone,
    int* __restrict__ gen, float* __restrict__ out)
{
    __shared__ union {
        float4 w[4][256];                     // 16 KB  (qk weights)
        float2 ks[TT];                        // 32 KB  (argmax K prefix)
        struct { int n; int g[4095]; } hits;  // 16 KB  (vrow rep list)
    } sm;

    const int tid  = threadIdx.x;
    const int bid  = blockIdx.x;
    const int wave = tid >> 6, lane = tid & 63;

    // Generation-XOR'd stamp: immune to stale stamps AND any byte-repeated
    // poison pattern (expv != memory content unless stamped THIS dispatch).
    const int expv = MAGIC ^ aload(gen);

    // ---------------- phase 0: Q,K projection (blocks 0..511, 32 rows) ------
    if (bid < 512) {
        sm.w[0][tid] = ((const float4*)(wq))[tid];
        sm.w[1][tid] = ((const float4*)(wq + DM))[tid];
        sm.w[2][tid] = ((const float4*)(wk))[tid];
        sm.w[3][tid] = ((const float4*)(wk + DM))[tid];
        if (tid < 32) {                       // init control state for my rows
            const int rg = bid * 32 + tid;
            astore(&rep[rg], SENT);
            astore(&idx[rg], -1);
            astore(&rowdone[rg], 0);
        }
        __syncthreads();

        #pragma unroll
        for (int rr = 0; rr < 8; ++rr) {
            const int row = bid * 32 + wave * 8 + rr;
            const float4* xr = (const float4*)(x + (size_t)row * DM);
            float s0 = 0.f, s1 = 0.f, s2 = 0.f, s3 = 0.f;
            #pragma unroll
            for (int j = 0; j < 4; ++j) {
                const float4 xv = xr[j * 64 + lane];
                s0 += dot4(xv, sm.w[0][j * 64 + lane]);
                s1 += dot4(xv, sm.w[1][j * 64 + lane]);
                s2 += dot4(xv, sm.w[2][j * 64 + lane]);
                s3 += dot4(xv, sm.w[3][j * 64 + lane]);
            }
            #pragma unroll
            for (int off = 32; off > 0; off >>= 1) {
                s0 += __shfl_down(s0, off);
                s1 += __shfl_down(s1, off);
                s2 += __shfl_down(s2, off);
                s3 += __shfl_down(s3, off);
            }
            if (lane == 0) {
                astore64(&Qu[row], packf2(s0, s1));
                astore64(&Ku[row], packf2(s2, s3));
            }
        }
        __syncthreads();                      // drains all waves' stores
        if (tid == 0) astore(&chunkdone[bid], expv);
    }

    // ---------------- phase 1: causal argmax (2 paired tiles per block) -----
    const float* Kf = (const float*)Ku;
    const float* Qf = (const float*)Qu;
    for (int pp = 0; pp < 2; ++pp) {
        const int p = bid * 2 + pp;           // 0..2047
        const int b = p >> 9, j = p & 511;    // pair: tg = 1023-j (big), j
        const int cmax = ((1023 - j) * 4 + 3) >> 5;     // chunks 0..cmax needed
        if (tid <= cmax) spin_eq(&chunkdone[b * 128 + tid], expv);
        __syncthreads();

        const int nfill4 = (((1023 - j) * 4 + 4) >> 1);
        const float4* kb4 = (const float4*)(Kf + (size_t)b * TT * 2);
        float4* ks4 = (float4*)sm.ks;
        for (int i = tid; i < nfill4; i += 256) ks4[i] = kb4[i];
        __syncthreads();

        const float4* kp = (const float4*)sm.ks;   // pair q -> points 2q,2q+1
        #pragma unroll
        for (int u = 0; u < 2; ++u) {
            const int tg = u ? j : (1023 - j);
            const int t = tg * 4 + wave;
            const float2 q = ((const float2*)Qf)[b * TT + t];

            float best = -INFINITY;
            int bi = 0x7fffffff;
            int pq = lane;
            while (2 * (pq + 64) + 1 <= t) {
                const float4 a = kp[pq];
                const float4 c = kp[pq + 64];
                const float c0 = q.x * a.x + q.y * a.y;
                const float c1 = q.x * a.z + q.y * a.w;
                const float c2 = q.x * c.x + q.y * c.y;
                const float c3 = q.x * c.z + q.y * c.w;
                if (c0 > best) { best = c0; bi = 2 * pq; }
                if (c1 > best) { best = c1; bi = 2 * pq + 1; }
                if (c2 > best) { best = c2; bi = 2 * (pq + 64); }
                if (c3 > best) { best = c3; bi = 2 * (pq + 64) + 1; }
                pq += 128;
            }
            while (2 * pq <= t) {
                const float4 a = kp[pq];
                const float c0 = q.x * a.x + q.y * a.y;
                if (c0 > best) { best = c0; bi = 2 * pq; }
                if (2 * pq + 1 <= t) {
                    const float c1 = q.x * a.z + q.y * a.w;
                    if (c1 > best) { best = c1; bi = 2 * pq + 1; }
                }
                pq += 64;
            }
            #pragma unroll
            for (int off = 32; off > 0; off >>= 1) {
                const float ov = __shfl_down(best, off);
                const int   oi = __shfl_down(bi, off);
                if (ov > best || (ov == best && oi < bi)) { best = ov; bi = oi; }
            }
            if (lane == 0) {
                astore(&idx[b * TT + t], bi);
                atomicMin(&rep[b * TT + bi], t);
            }
        }
        __syncthreads();                      // readers done before restage
    }
    if (tid == 0) astore(&blkdone[bid], expv);

    // ---------------- phase 2: V rows for representatives -------------------
    const int slice = bid >> 4;               // W_V cols slice*16..slice*16+15
    const int usub  = bid & 15;               // t-partition g%16==usub
    const int e0 = slice * 16 + wave * 4;
    float4 w[4][4];
    #pragma unroll
    for (int r = 0; r < 4; ++r) {
        const float4* wr = (const float4*)(wv + (size_t)(e0 + r) * DM);
        #pragma unroll
        for (int jj = 0; jj < 4; ++jj) w[r][jj] = wr[jj * 64 + lane];
    }
    {   // wait for ALL argmax stamps (256 threads x 4 parallel polls)
        #pragma unroll
        for (int k = 0; k < 4; ++k) spin_eq(&blkdone[tid + 256 * k], expv);
    }
    __syncthreads();
    if (tid == 0) sm.hits.n = 0;
    __syncthreads();
    #pragma unroll
    for (int k = 0; k < 4; ++k) {             // scan my 4 of 1024 g's
        const int m = tid + 256 * k;
        const int g = usub + (m << 4);
        const int s = aload(&idx[g]);
        const int b2 = g >> 12;
        if (aload(&rep[(b2 << 12) + s]) == (g & (TT - 1))) {
            const int pos = atomicAdd(&sm.hits.n, 1);
            sm.hits.g[pos] = g;
        }
    }
    __syncthreads();
    const int nh = sm.hits.n;
    for (int h = 0; h < nh; ++h) {
        const int g  = sm.hits.g[h];
        const int b2 = g >> 12;
        const int s  = aload(&idx[g]);
        const int bs = (b2 << 12) + s;
        const float4* xr = (const float4*)(x + (size_t)bs * DM);
        float4 xv[4];
        #pragma unroll
        for (int jj = 0; jj < 4; ++jj) xv[jj] = xr[jj * 64 + lane];
        float s0 = 0.f, s1 = 0.f, s2 = 0.f, s3 = 0.f;
        #pragma unroll
        for (int jj = 0; jj < 4; ++jj) {
            s0 += dot4(w[0][jj], xv[jj]);
            s1 += dot4(w[1][jj], xv[jj]);
            s2 += dot4(w[2][jj], xv[jj]);
            s3 += dot4(w[3][jj], xv[jj]);
        }
        #pragma unroll
        for (int off = 32; off > 0; off >>= 1) {
            s0 += __shfl_down(s0, off);
            s1 += __shfl_down(s1, off);
            s2 += __shfl_down(s2, off);
            s3 += __shfl_down(s3, off);
        }
        if (lane == 0) {
            unsigned long long* op = (unsigned long long*)(out + (size_t)g * DM + e0);
            astore64(op,     packf2(s0, s1));
            astore64(op + 1, packf2(s2, s3));
        }
        __syncthreads();                      // drains all 4 waves' row stores
        if (tid == 0) atomicAdd(&rowdone[bs], 1);   // -> 64 when complete
    }

    // ---------------- phase 3: broadcast representative rows ----------------
    for (int r4 = 0; r4 < 4; ++r4) {
        const int g  = bid * 16 + r4 * 4 + wave;
        const int b2 = g >> 12, tl = g & (TT - 1);
        const int s  = aload(&idx[g]);
        const int bs = (b2 << 12) + s;
        const int r  = aload(&rep[bs]);
        if (r == tl) continue;                // wave-uniform
        int it = 0;
        while (aload(&rowdone[bs]) != 64) {
            __builtin_amdgcn_s_sleep(8);
            if (++it > (1 << 21)) break;
        }
        asm volatile("" ::: "memory");
        const float4* src = (const float4*)(out + ((size_t)(b2 * TT + r)) * DM);
        float4* dst = (float4*)(out + (size_t)g * DM);
        #pragma unroll
        for (int k2 = 0; k2 < 4; ++k2) dst[k2 * 64 + lane] = src[k2 * 64 + lane];
    }

    __syncthreads();
    if (bid == 0 && tid == 0) atomicAdd(gen, 1);   // new generation next run
}

extern "C" void kernel_launch(void* const* d_in, const int* in_sizes, int n_in,
                              void* d_out, int out_size, void* d_ws, size_t ws_size,
                              hipStream_t stream) {
    const float* x  = (const float*)d_in[0];
    const float* wq = (const float*)d_in[1];
    const float* wk = (const float*)d_in[2];
    const float* wv = (const float*)d_in[3];
    float* out = (float*)d_out;

    char* ws = (char*)d_ws;
    unsigned long long* Qu = (unsigned long long*)(ws);
    unsigned long long* Ku = (unsigned long long*)(ws + 131072);
    int* idx       = (int*)(ws + 262144);
    int* rep       = (int*)(ws + 327680);
    int* rowdone   = (int*)(ws + 393216);
    int* chunkdone = (int*)(ws + 458752);
    int* blkdone   = (int*)(ws + 460800);
    int* gen       = (int*)(ws + 464896);

    mega_kernel<<<NBLK, 256, 0, stream>>>(x, wq, wk, wv, Qu, Ku,
                                          idx, rep, rowdone,
                                          chunkdone, blkdone, gen, out);
}

// Round 7
// 229.219 us; speedup vs baseline: 1.0382x; 1.0382x over previous
//
#include <hip/hip_runtime.h>
#include <math.h>

#define TT 4096
#define DM 1024
#define BB 4
#define BT (BB * TT)
#define SENT  0x7f7f7f7f
#define MAGIC 0x17C3A5E9

// ws layout (bytes):
//   Qu       : u64[BT]   @ 0       (131072)  packed float2 (q0,q1)
//   Ku       : u64[BT]   @ 131072  (131072)  packed float2 (k0,k1)
//   idx      : int[BT]   @ 262144  (65536)
//   rep      : int[BT]   @ 327680  (65536)
//   rowdone  : int[BT]   @ 393216  (65536)
//   chunkdone: int[512]  @ 458752  (2048)    stamp per 32-row chunk
//   gen      : int       @ 460800  (4)       generation word (bumped at end)

__device__ __forceinline__ float dot4(const float4 a, const float4 b) {
    return a.x * b.x + a.y * b.y + a.z * b.z + a.w * b.w;
}
__device__ __forceinline__ int aload(const int* p) {
    return __hip_atomic_load((int*)p, __ATOMIC_RELAXED, __HIP_MEMORY_SCOPE_AGENT);
}
__device__ __forceinline__ void astore(int* p, int v) {
    __hip_atomic_store(p, v, __ATOMIC_RELAXED, __HIP_MEMORY_SCOPE_AGENT);
}
__device__ __forceinline__ void astore64(unsigned long long* p, unsigned long long v) {
    __hip_atomic_store(p, v, __ATOMIC_RELAXED, __HIP_MEMORY_SCOPE_AGENT);
}
__device__ __forceinline__ unsigned long long packf2(float a, float b) {
    union { float2 f; unsigned long long u; } cv;
    cv.f = make_float2(a, b);
    return cv.u;
}
__device__ __forceinline__ void spin_eq(const int* p, int v) {
    int it = 0;
    while (__hip_atomic_load((int*)p, __ATOMIC_RELAXED, __HIP_MEMORY_SCOPE_AGENT) != v) {
        __builtin_amdgcn_s_sleep(8);
        if (++it > (1 << 21)) break;   // fail visibly, never hang
    }
}

// ============================================================================
// Kernel 1: qk projection + causal argmax (round-5-validated phases 0+1).
// 1024 blocks x 256. blocks 0..511 produce Q/K (32 rows each, chunkdone
// stamps); all blocks then run argmax on 2 paired tiles with prefix spins.
// ============================================================================
__global__ __launch_bounds__(256, 4) void qk_am_kernel(
    const float* __restrict__ x, const float* __restrict__ wq,
    const float* __restrict__ wk,
    unsigned long long* __restrict__ Qu, unsigned long long* __restrict__ Ku,
    int* __restrict__ idx, int* __restrict__ rep, int* __restrict__ rowdone,
    int* __restrict__ chunkdone, const int* __restrict__ gen)
{
    __shared__ union {
        float4 w[4][256];   // 16 KB (qk weights)
        float2 ks[TT];      // 32 KB (argmax K prefix)
    } sm;

    const int tid  = threadIdx.x;
    const int bid  = blockIdx.x;
    const int wave = tid >> 6, lane = tid & 63;

    // Generation-XOR'd stamp (validated r5): immune to stale stamps/poison.
    const int expv = MAGIC ^ aload(gen);

    // ---------------- phase 0: Q,K projection (blocks 0..511, 32 rows) ------
    if (bid < 512) {
        sm.w[0][tid] = ((const float4*)(wq))[tid];
        sm.w[1][tid] = ((const float4*)(wq + DM))[tid];
        sm.w[2][tid] = ((const float4*)(wk))[tid];
        sm.w[3][tid] = ((const float4*)(wk + DM))[tid];
        if (tid < 32) {                       // init control state for my rows
            const int rg = bid * 32 + tid;
            astore(&rep[rg], SENT);
            astore(&idx[rg], -1);
            astore(&rowdone[rg], 0);
        }
        __syncthreads();

        #pragma unroll
        for (int rr = 0; rr < 8; ++rr) {
            const int row = bid * 32 + wave * 8 + rr;
            const float4* xr = (const float4*)(x + (size_t)row * DM);
            float s0 = 0.f, s1 = 0.f, s2 = 0.f, s3 = 0.f;
            #pragma unroll
            for (int j = 0; j < 4; ++j) {
                const float4 xv = xr[j * 64 + lane];
                s0 += dot4(xv, sm.w[0][j * 64 + lane]);
                s1 += dot4(xv, sm.w[1][j * 64 + lane]);
                s2 += dot4(xv, sm.w[2][j * 64 + lane]);
                s3 += dot4(xv, sm.w[3][j * 64 + lane]);
            }
            #pragma unroll
            for (int off = 32; off > 0; off >>= 1) {
                s0 += __shfl_down(s0, off);
                s1 += __shfl_down(s1, off);
                s2 += __shfl_down(s2, off);
                s3 += __shfl_down(s3, off);
            }
            if (lane == 0) {
                astore64(&Qu[row], packf2(s0, s1));
                astore64(&Ku[row], packf2(s2, s3));
            }
        }
        __syncthreads();                      // drains all waves' stores
        if (tid == 0) astore(&chunkdone[bid], expv);
    }

    // ---------------- phase 1: causal argmax (2 paired tiles per block) -----
    const float* Kf = (const float*)Ku;
    const float* Qf = (const float*)Qu;
    for (int pp = 0; pp < 2; ++pp) {
        const int p = bid * 2 + pp;           // 0..2047
        const int b = p >> 9, j = p & 511;    // pair: tg = 1023-j (big), j
        const int cmax = ((1023 - j) * 4 + 3) >> 5;     // chunks 0..cmax needed
        if (tid <= cmax) spin_eq(&chunkdone[b * 128 + tid], expv);
        __syncthreads();

        const int nfill4 = (((1023 - j) * 4 + 4) >> 1);
        const float4* kb4 = (const float4*)(Kf + (size_t)b * TT * 2);
        float4* ks4 = (float4*)sm.ks;
        for (int i = tid; i < nfill4; i += 256) ks4[i] = kb4[i];
        __syncthreads();

        const float4* kp = (const float4*)sm.ks;   // pair q -> points 2q,2q+1
        #pragma unroll
        for (int u = 0; u < 2; ++u) {
            const int tg = u ? j : (1023 - j);
            const int t = tg * 4 + wave;
            const float2 q = ((const float2*)Qf)[b * TT + t];

            float best = -INFINITY;
            int bi = 0x7fffffff;
            int pq = lane;
            while (2 * (pq + 64) + 1 <= t) {
                const float4 a = kp[pq];
                const float4 c = kp[pq + 64];
                const float c0 = q.x * a.x + q.y * a.y;
                const float c1 = q.x * a.z + q.y * a.w;
                const float c2 = q.x * c.x + q.y * c.y;
                const float c3 = q.x * c.z + q.y * c.w;
                if (c0 > best) { best = c0; bi = 2 * pq; }
                if (c1 > best) { best = c1; bi = 2 * pq + 1; }
                if (c2 > best) { best = c2; bi = 2 * (pq + 64); }
                if (c3 > best) { best = c3; bi = 2 * (pq + 64) + 1; }
                pq += 128;
            }
            while (2 * pq <= t) {
                const float4 a = kp[pq];
                const float c0 = q.x * a.x + q.y * a.y;
                if (c0 > best) { best = c0; bi = 2 * pq; }
                if (2 * pq + 1 <= t) {
                    const float c1 = q.x * a.z + q.y * a.w;
                    if (c1 > best) { best = c1; bi = 2 * pq + 1; }
                }
                pq += 64;
            }
            #pragma unroll
            for (int off = 32; off > 0; off >>= 1) {
                const float ov = __shfl_down(best, off);
                const int   oi = __shfl_down(bi, off);
                if (ov > best || (ov == best && oi < bi)) { best = ov; bi = oi; }
            }
            if (lane == 0) {
                astore(&idx[b * TT + t], bi);
                atomicMin(&rep[b * TT + bi], t);
            }
        }
        __syncthreads();                      // readers done before restage
    }
}

// ============================================================================
// Kernel 2: V rows for representatives + broadcast (round-5-validated
// phases 2+3; the blkdone wait is replaced by the kernel boundary).
// Phase 2 has NO spins -> deadlock-proof regardless of residency.
// ============================================================================
__global__ __launch_bounds__(256, 4) void vrow_gather_kernel(
    const float* __restrict__ x, const float* __restrict__ wv,
    const int* __restrict__ idx, const int* __restrict__ rep,
    int* __restrict__ rowdone, int* __restrict__ gen,
    float* __restrict__ out)
{
    __shared__ int hits_n;
    __shared__ int hits_g[4096];

    const int tid  = threadIdx.x;
    const int bid  = blockIdx.x;
    const int wave = tid >> 6, lane = tid & 63;

    // ---------------- phase 2: V rows for representatives -------------------
    const int slice = bid >> 4;               // out cols slice*16..slice*16+15
    const int usub  = bid & 15;               // t-partition g%16==usub
    const int e0 = slice * 16 + wave * 4;
    float4 w[4][4];
    #pragma unroll
    for (int r = 0; r < 4; ++r) {
        const float4* wr = (const float4*)(wv + (size_t)(e0 + r) * DM);
        #pragma unroll
        for (int jj = 0; jj < 4; ++jj) w[r][jj] = wr[jj * 64 + lane];
    }
    if (tid == 0) hits_n = 0;
    __syncthreads();
    #pragma unroll
    for (int k = 0; k < 4; ++k) {             // scan my 4 of 1024 g's
        const int m4 = tid + 256 * k;
        const int g = usub + (m4 << 4);
        const int s = aload(&idx[g]);
        const int b2 = g >> 12;
        if (aload(&rep[(b2 << 12) + s]) == (g & (TT - 1))) {
            const int pos = atomicAdd(&hits_n, 1);
            hits_g[pos] = g;
        }
    }
    __syncthreads();
    const int nh = hits_n;
    for (int h = 0; h < nh; ++h) {
        const int g  = hits_g[h];
        const int b2 = g >> 12;
        const int s  = aload(&idx[g]);
        const int bs = (b2 << 12) + s;
        const float4* xr = (const float4*)(x + (size_t)bs * DM);
        float4 xv[4];
        #pragma unroll
        for (int jj = 0; jj < 4; ++jj) xv[jj] = xr[jj * 64 + lane];
        float s0 = 0.f, s1 = 0.f, s2 = 0.f, s3 = 0.f;
        #pragma unroll
        for (int jj = 0; jj < 4; ++jj) {
            s0 += dot4(w[0][jj], xv[jj]);
            s1 += dot4(w[1][jj], xv[jj]);
            s2 += dot4(w[2][jj], xv[jj]);
            s3 += dot4(w[3][jj], xv[jj]);
        }
        #pragma unroll
        for (int off = 32; off > 0; off >>= 1) {
            s0 += __shfl_down(s0, off);
            s1 += __shfl_down(s1, off);
            s2 += __shfl_down(s2, off);
            s3 += __shfl_down(s3, off);
        }
        if (lane == 0) {
            unsigned long long* op = (unsigned long long*)(out + (size_t)g * DM + e0);
            astore64(op,     packf2(s0, s1));
            astore64(op + 1, packf2(s2, s3));
        }
        __syncthreads();                      // all 4 waves' row stores drained
        if (tid == 0) atomicAdd(&rowdone[bs], 1);   // -> 64 when row complete
    }

    // ---------------- phase 3: broadcast my 16 rows -------------------------
    for (int r4 = 0; r4 < 4; ++r4) {
        const int g  = bid * 16 + r4 * 4 + wave;
        const int b2 = g >> 12, tl = g & (TT - 1);
        const int s  = aload(&idx[g]);
        const int bs = (b2 << 12) + s;
        const int r  = aload(&rep[bs]);
        if (r == tl) continue;                // wave-uniform: I am the rep row
        int it = 0;
        while (aload(&rowdone[bs]) != 64) {
            __builtin_amdgcn_s_sleep(8);
            if (++it > (1 << 21)) break;
        }
        asm volatile("" ::: "memory");
        const float4* src = (const float4*)(out + ((size_t)(b2 * TT + r)) * DM);
        float4* dst = (float4*)(out + (size_t)g * DM);
        #pragma unroll
        for (int k2 = 0; k2 < 4; ++k2) dst[k2 * 64 + lane] = src[k2 * 64 + lane];
    }

    __syncthreads();
    if (bid == 0 && tid == 0) atomicAdd(gen, 1);   // new generation next run
}

extern "C" void kernel_launch(void* const* d_in, const int* in_sizes, int n_in,
                              void* d_out, int out_size, void* d_ws, size_t ws_size,
                              hipStream_t stream) {
    const float* x  = (const float*)d_in[0];
    const float* wq = (const float*)d_in[1];
    const float* wk = (const float*)d_in[2];
    const float* wv = (const float*)d_in[3];
    float* out = (float*)d_out;

    char* ws = (char*)d_ws;
    unsigned long long* Qu = (unsigned long long*)(ws);
    unsigned long long* Ku = (unsigned long long*)(ws + 131072);
    int* idx       = (int*)(ws + 262144);
    int* rep       = (int*)(ws + 327680);
    int* rowdone   = (int*)(ws + 393216);
    int* chunkdone = (int*)(ws + 458752);
    int* gen       = (int*)(ws + 460800);

    qk_am_kernel<<<1024, 256, 0, stream>>>(x, wq, wk, Qu, Ku,
                                           idx, rep, rowdone, chunkdone, gen);
    vrow_gather_kernel<<<1024, 256, 0, stream>>>(x, wv, idx, rep,
                                                 rowdone, gen, out);
}

// Round 8
// 217.544 us; speedup vs baseline: 1.0939x; 1.0537x over previous
//
#include <hip/hip_runtime.h>
#include <math.h>

#define TT 4096
#define DM 1024
#define BB 4
#define BT (BB * TT)
#define SENT  0x7f7f7f7f
#define MAGIC 0x17C3A5E9

// ws layout (bytes):
//   Qu       : u64[BT]   @ 0       (131072)  packed float2 (q0,q1)
//   Ku       : u64[BT]   @ 131072  (131072)  packed float2 (k0,k1)
//   idx      : int[BT]   @ 262144  (65536)
//   rep      : int[BT]   @ 327680  (65536)
//   rowdone  : int[BT]   @ 393216  (65536)   (initialized, unused downstream)
//   chunkdone: int[512]  @ 458752  (2048)    stamp per 32-row chunk
//   gen      : int       @ 460800  (4)       generation word

__device__ __forceinline__ float dot4(const float4 a, const float4 b) {
    return a.x * b.x + a.y * b.y + a.z * b.z + a.w * b.w;
}
__device__ __forceinline__ int aload(const int* p) {
    return __hip_atomic_load((int*)p, __ATOMIC_RELAXED, __HIP_MEMORY_SCOPE_AGENT);
}
__device__ __forceinline__ void astore(int* p, int v) {
    __hip_atomic_store(p, v, __ATOMIC_RELAXED, __HIP_MEMORY_SCOPE_AGENT);
}
__device__ __forceinline__ void astore64(unsigned long long* p, unsigned long long v) {
    __hip_atomic_store(p, v, __ATOMIC_RELAXED, __HIP_MEMORY_SCOPE_AGENT);
}
__device__ __forceinline__ unsigned long long packf2(float a, float b) {
    union { float2 f; unsigned long long u; } cv;
    cv.f = make_float2(a, b);
    return cv.u;
}
__device__ __forceinline__ void spin_eq(const int* p, int v) {
    int it = 0;
    while (__hip_atomic_load((int*)p, __ATOMIC_RELAXED, __HIP_MEMORY_SCOPE_AGENT) != v) {
        __builtin_amdgcn_s_sleep(8);
        if (++it > (1 << 21)) break;   // fail visibly, never hang
    }
}

// ============================================================================
// Kernel 1: qk projection + causal argmax — VERBATIM from round 7 (passed).
// ============================================================================
__global__ __launch_bounds__(256, 4) void qk_am_kernel(
    const float* __restrict__ x, const float* __restrict__ wq,
    const float* __restrict__ wk,
    unsigned long long* __restrict__ Qu, unsigned long long* __restrict__ Ku,
    int* __restrict__ idx, int* __restrict__ rep, int* __restrict__ rowdone,
    int* __restrict__ chunkdone, const int* __restrict__ gen)
{
    __shared__ union {
        float4 w[4][256];   // 16 KB (qk weights)
        float2 ks[TT];      // 32 KB (argmax K prefix)
    } sm;

    const int tid  = threadIdx.x;
    const int bid  = blockIdx.x;
    const int wave = tid >> 6, lane = tid & 63;

    // Generation-XOR'd stamp (validated r5/r7): immune to stale stamps/poison.
    const int expv = MAGIC ^ aload(gen);

    // ---------------- phase 0: Q,K projection (blocks 0..511, 32 rows) ------
    if (bid < 512) {
        sm.w[0][tid] = ((const float4*)(wq))[tid];
        sm.w[1][tid] = ((const float4*)(wq + DM))[tid];
        sm.w[2][tid] = ((const float4*)(wk))[tid];
        sm.w[3][tid] = ((const float4*)(wk + DM))[tid];
        if (tid < 32) {
            const int rg = bid * 32 + tid;
            astore(&rep[rg], SENT);
            astore(&idx[rg], -1);
            astore(&rowdone[rg], 0);
        }
        __syncthreads();

        #pragma unroll
        for (int rr = 0; rr < 8; ++rr) {
            const int row = bid * 32 + wave * 8 + rr;
            const float4* xr = (const float4*)(x + (size_t)row * DM);
            float s0 = 0.f, s1 = 0.f, s2 = 0.f, s3 = 0.f;
            #pragma unroll
            for (int j = 0; j < 4; ++j) {
                const float4 xv = xr[j * 64 + lane];
                s0 += dot4(xv, sm.w[0][j * 64 + lane]);
                s1 += dot4(xv, sm.w[1][j * 64 + lane]);
                s2 += dot4(xv, sm.w[2][j * 64 + lane]);
                s3 += dot4(xv, sm.w[3][j * 64 + lane]);
            }
            #pragma unroll
            for (int off = 32; off > 0; off >>= 1) {
                s0 += __shfl_down(s0, off);
                s1 += __shfl_down(s1, off);
                s2 += __shfl_down(s2, off);
                s3 += __shfl_down(s3, off);
            }
            if (lane == 0) {
                astore64(&Qu[row], packf2(s0, s1));
                astore64(&Ku[row], packf2(s2, s3));
            }
        }
        __syncthreads();
        if (tid == 0) astore(&chunkdone[bid], expv);
    }

    // ---------------- phase 1: causal argmax (2 paired tiles per block) -----
    const float* Kf = (const float*)Ku;
    const float* Qf = (const float*)Qu;
    for (int pp = 0; pp < 2; ++pp) {
        const int p = bid * 2 + pp;           // 0..2047
        const int b = p >> 9, j = p & 511;    // pair: tg = 1023-j (big), j
        const int cmax = ((1023 - j) * 4 + 3) >> 5;
        if (tid <= cmax) spin_eq(&chunkdone[b * 128 + tid], expv);
        __syncthreads();

        const int nfill4 = (((1023 - j) * 4 + 4) >> 1);
        const float4* kb4 = (const float4*)(Kf + (size_t)b * TT * 2);
        float4* ks4 = (float4*)sm.ks;
        for (int i = tid; i < nfill4; i += 256) ks4[i] = kb4[i];
        __syncthreads();

        const float4* kp = (const float4*)sm.ks;
        #pragma unroll
        for (int u = 0; u < 2; ++u) {
            const int tg = u ? j : (1023 - j);
            const int t = tg * 4 + wave;
            const float2 q = ((const float2*)Qf)[b * TT + t];

            float best = -INFINITY;
            int bi = 0x7fffffff;
            int pq = lane;
            while (2 * (pq + 64) + 1 <= t) {
                const float4 a = kp[pq];
                const float4 c = kp[pq + 64];
                const float c0 = q.x * a.x + q.y * a.y;
                const float c1 = q.x * a.z + q.y * a.w;
                const float c2 = q.x * c.x + q.y * c.y;
                const float c3 = q.x * c.z + q.y * c.w;
                if (c0 > best) { best = c0; bi = 2 * pq; }
                if (c1 > best) { best = c1; bi = 2 * pq + 1; }
                if (c2 > best) { best = c2; bi = 2 * (pq + 64); }
                if (c3 > best) { best = c3; bi = 2 * (pq + 64) + 1; }
                pq += 128;
            }
            while (2 * pq <= t) {
                const float4 a = kp[pq];
                const float c0 = q.x * a.x + q.y * a.y;
                if (c0 > best) { best = c0; bi = 2 * pq; }
                if (2 * pq + 1 <= t) {
                    const float c1 = q.x * a.z + q.y * a.w;
                    if (c1 > best) { best = c1; bi = 2 * pq + 1; }
                }
                pq += 64;
            }
            #pragma unroll
            for (int off = 32; off > 0; off >>= 1) {
                const float ov = __shfl_down(best, off);
                const int   oi = __shfl_down(bi, off);
                if (ov > best || (ov == best && oi < bi)) { best = ov; bi = oi; }
            }
            if (lane == 0) {
                astore(&idx[b * TT + t], bi);
                atomicMin(&rep[b * TT + bi], t);
            }
        }
        __syncthreads();
    }
}

// ============================================================================
// Kernel 2: V rows for representatives — R7's phase 2 with the sync machinery
// deleted (kernel boundary guarantees idx/rep valid). Plain stores (R3-style).
// ============================================================================
__global__ __launch_bounds__(256, 4) void vrow_kernel(
    const float* __restrict__ x, const float* __restrict__ wv,
    const int* __restrict__ idx, const int* __restrict__ rep,
    float* __restrict__ out)
{
    __shared__ int hits_n;
    __shared__ int hits_g[4096];

    const int tid  = threadIdx.x;
    const int bid  = blockIdx.x;
    const int wave = tid >> 6, lane = tid & 63;

    const int slice = bid >> 4;               // out cols slice*16..slice*16+15
    const int usub  = bid & 15;               // t-partition g%16==usub
    const int e0 = slice * 16 + wave * 4;
    float4 w[4][4];
    #pragma unroll
    for (int r = 0; r < 4; ++r) {
        const float4* wr = (const float4*)(wv + (size_t)(e0 + r) * DM);
        #pragma unroll
        for (int jj = 0; jj < 4; ++jj) w[r][jj] = wr[jj * 64 + lane];
    }
    if (tid == 0) hits_n = 0;
    __syncthreads();
    #pragma unroll
    for (int k = 0; k < 4; ++k) {             // scan my 4 of 1024 g's
        const int m4 = tid + 256 * k;
        const int g = usub + (m4 << 4);
        const int s = idx[g];
        const int b2 = g >> 12;
        if (rep[(b2 << 12) + s] == (g & (TT - 1))) {
            const int pos = atomicAdd(&hits_n, 1);
            hits_g[pos] = g;
        }
    }
    __syncthreads();
    const int nh = hits_n;
    for (int h = 0; h < nh; ++h) {
        const int g  = hits_g[h];
        const int b2 = g >> 12;
        const int s  = idx[g];
        const int bs = (b2 << 12) + s;
        const float4* xr = (const float4*)(x + (size_t)bs * DM);
        float4 xv[4];
        #pragma unroll
        for (int jj = 0; jj < 4; ++jj) xv[jj] = xr[jj * 64 + lane];
        float s0 = 0.f, s1 = 0.f, s2 = 0.f, s3 = 0.f;
        #pragma unroll
        for (int jj = 0; jj < 4; ++jj) {
            s0 += dot4(w[0][jj], xv[jj]);
            s1 += dot4(w[1][jj], xv[jj]);
            s2 += dot4(w[2][jj], xv[jj]);
            s3 += dot4(w[3][jj], xv[jj]);
        }
        #pragma unroll
        for (int off = 32; off > 0; off >>= 1) {
            s0 += __shfl_down(s0, off);
            s1 += __shfl_down(s1, off);
            s2 += __shfl_down(s2, off);
            s3 += __shfl_down(s3, off);
        }
        if (lane == 0)
            *(float4*)(out + (size_t)g * DM + e0) = make_float4(s0, s1, s2, s3);
    }
}

// ============================================================================
// Kernel 3: broadcast representative rows — VERBATIM from round 3 (passed),
// plus the generation bump at the end.
// ============================================================================
__global__ __launch_bounds__(256) void gather_kernel(const int* __restrict__ idx,
                                                     const int* __restrict__ rep,
                                                     int* __restrict__ gen,
                                                     float* __restrict__ out) {
    const int tid = threadIdx.x, wave = tid >> 6, lane = tid & 63;
    const int bt = blockIdx.x * 4 + wave;
    const int b = bt >> 12, t = bt & (TT - 1);
    const int s = idx[bt];
    const int r = rep[b * TT + s];
    if (blockIdx.x == 0 && tid == 0) atomicAdd(gen, 1);   // next-run generation
    if (r == t) return;                       // wave-uniform
    const float4* src = (const float4*)(out + ((size_t)(b * TT + r)) * DM);
    float4* dst = (float4*)(out + (size_t)bt * DM);
    #pragma unroll
    for (int k = 0; k < 4; ++k) dst[k * 64 + lane] = src[k * 64 + lane];
}

extern "C" void kernel_launch(void* const* d_in, const int* in_sizes, int n_in,
                              void* d_out, int out_size, void* d_ws, size_t ws_size,
                              hipStream_t stream) {
    const float* x  = (const float*)d_in[0];
    const float* wq = (const float*)d_in[1];
    const float* wk = (const float*)d_in[2];
    const float* wv = (const float*)d_in[3];
    float* out = (float*)d_out;

    char* ws = (char*)d_ws;
    unsigned long long* Qu = (unsigned long long*)(ws);
    unsigned long long* Ku = (unsigned long long*)(ws + 131072);
    int* idx       = (int*)(ws + 262144);
    int* rep       = (int*)(ws + 327680);
    int* rowdone   = (int*)(ws + 393216);
    int* chunkdone = (int*)(ws + 458752);
    int* gen       = (int*)(ws + 460800);

    qk_am_kernel<<<1024, 256, 0, stream>>>(x, wq, wk, Qu, Ku,
                                           idx, rep, rowdone, chunkdone, gen);
    vrow_kernel<<<1024, 256, 0, stream>>>(x, wv, idx, rep, out);
    gather_kernel<<<BT / 4, 256, 0, stream>>>(idx, rep, gen, out);
}

// Round 9
// 216.365 us; speedup vs baseline: 1.0999x; 1.0054x over previous
//
#include <hip/hip_runtime.h>
#include <math.h>

#define TT 4096
#define DM 1024
#define BB 4
#define BT (BB * TT)
#define SENTINEL 0x7fffffff

// ws layout (bytes):
//   Q    : float[BT*2]  @ 0        (131072)  (interleaved q0,q1 pairs)
//   K    : float[BT*2]  @ 131072   (131072)  (interleaved k0,k1 pairs)
//   idx  : int[BT]      @ 262144   (65536)
//   rep  : int[BT]      @ 327680   (65536)

__device__ __forceinline__ float dot4(const float4 a, const float4 b) {
    return a.x * b.x + a.y * b.y + a.z * b.z + a.w * b.w;
}

// ---------- Kernel 1: Q,K projection. 1024 blocks x 16 rows (wave does 4).
//            Weights staged once per block in LDS. Inits rep[] only. ----------
__global__ __launch_bounds__(256, 4) void qk_kernel(const float* __restrict__ x,
                                                    const float* __restrict__ wq,
                                                    const float* __restrict__ wk,
                                                    float* __restrict__ Q,
                                                    float* __restrict__ K,
                                                    int* __restrict__ rep) {
    __shared__ float4 ws4[4][256];   // wq row0, wq row1, wk row0, wk row1 (16 KB)
    const int tid = threadIdx.x;
    const int row0 = blockIdx.x * 16;

    ws4[0][tid] = ((const float4*)(wq))[tid];
    ws4[1][tid] = ((const float4*)(wq + DM))[tid];
    ws4[2][tid] = ((const float4*)(wk))[tid];
    ws4[3][tid] = ((const float4*)(wk + DM))[tid];
    if (tid < 16) rep[row0 + tid] = SENTINEL;
    __syncthreads();

    const int wave = tid >> 6, lane = tid & 63;

    #pragma unroll
    for (int g = 0; g < 4; ++g) {
        const int row = row0 + g * 4 + wave;
        const float4* xr = (const float4*)(x + (size_t)row * DM);

        float s0 = 0.f, s1 = 0.f, s2 = 0.f, s3 = 0.f;
        #pragma unroll
        for (int j = 0; j < 4; ++j) {
            const float4 xv = xr[j * 64 + lane];
            s0 += dot4(xv, ws4[0][j * 64 + lane]);
            s1 += dot4(xv, ws4[1][j * 64 + lane]);
            s2 += dot4(xv, ws4[2][j * 64 + lane]);
            s3 += dot4(xv, ws4[3][j * 64 + lane]);
        }
        #pragma unroll
        for (int off = 32; off > 0; off >>= 1) {
            s0 += __shfl_down(s0, off);
            s1 += __shfl_down(s1, off);
            s2 += __shfl_down(s2, off);
            s3 += __shfl_down(s3, off);
        }
        if (lane == 0) {
            ((float2*)Q)[row] = make_float2(s0, s1);
            ((float2*)K)[row] = make_float2(s2, s3);
        }
    }
}

// ---------- Kernel 2: causal argmax. 1024 blocks; block (b, m) stages ONE
//            prefix (covers tile 1023-2m) and scans 4 tiles
//            {1023-2m, 1022-2m, 2m, 2m+1} — exact partition, constant work,
//            half the staging traffic of the 2-tile pairing. ----------
__global__ __launch_bounds__(256, 4) void argmax_kernel(const float* __restrict__ Q,
                                                        const float* __restrict__ K,
                                                        int* __restrict__ idx,
                                                        int* __restrict__ rep) {
    __shared__ float2 ks[TT];   // 32 KB
    const int b = blockIdx.x >> 8;
    const int m = blockIdx.x & 255;
    const int tid = threadIdx.x;

    // stage prefix for the biggest tile (1023-2m): points 0 .. 4095-8m
    const int nfill4 = 2048 - 4 * m;          // float4 count
    const float4* kb4 = (const float4*)(K + (size_t)b * TT * 2);
    float4* ks4 = (float4*)ks;
    for (int i = tid; i < nfill4; i += 256) ks4[i] = kb4[i];
    __syncthreads();

    const int wave = tid >> 6, lane = tid & 63;
    const float4* kp = (const float4*)ks;     // pair p -> points 2p, 2p+1

    const int tgs[4] = {1023 - 2 * m, 1022 - 2 * m, 2 * m, 2 * m + 1};
    #pragma unroll
    for (int u = 0; u < 4; ++u) {
        const int tg = tgs[u];
        const int t = tg * 4 + wave;
        const float2 q = ((const float2*)Q)[b * TT + t];

        float best = -INFINITY;
        int bi = SENTINEL;
        int p = lane;
        // main: both pairs fully in range; in-lane ascending s order + strict '>'
        while (2 * (p + 64) + 1 <= t) {
            const float4 a = kp[p];
            const float4 c = kp[p + 64];
            const float c0 = q.x * a.x + q.y * a.y;
            const float c1 = q.x * a.z + q.y * a.w;
            const float c2 = q.x * c.x + q.y * c.y;
            const float c3 = q.x * c.z + q.y * c.w;
            if (c0 > best) { best = c0; bi = 2 * p; }
            if (c1 > best) { best = c1; bi = 2 * p + 1; }
            if (c2 > best) { best = c2; bi = 2 * (p + 64); }
            if (c3 > best) { best = c3; bi = 2 * (p + 64) + 1; }
            p += 128;
        }
        while (2 * p <= t) {
            const float4 a = kp[p];
            const float c0 = q.x * a.x + q.y * a.y;
            if (c0 > best) { best = c0; bi = 2 * p; }
            if (2 * p + 1 <= t) {
                const float c1 = q.x * a.z + q.y * a.w;
                if (c1 > best) { best = c1; bi = 2 * p + 1; }
            }
            p += 64;
        }
        // cross-lane argmax, first-occurrence tie-break (smaller index wins)
        #pragma unroll
        for (int off = 32; off > 0; off >>= 1) {
            const float ov = __shfl_down(best, off);
            const int   oi = __shfl_down(bi, off);
            if (ov > best || (ov == best && oi < bi)) { best = ov; bi = oi; }
        }
        if (lane == 0) {
            idx[b * TT + t] = bi;
            atomicMin(&rep[b * TT + bi], t);
        }
        // no __syncthreads needed: LDS is read-only across all 4 tiles
    }
}

// ---------- Kernel 3: V rows for representatives (verbatim round-8, passed).
//            Block (slice, usub): scans g with g%16==usub, computes cols
//            e0..e0+15 for each representative row it finds. ----------
__global__ __launch_bounds__(256, 4) void vrow_kernel(const float* __restrict__ x,
                                                      const float* __restrict__ wv,
                                                      const int* __restrict__ idx,
                                                      const int* __restrict__ rep,
                                                      float* __restrict__ out) {
    __shared__ int hits_n;
    __shared__ int hits_g[4096];

    const int tid  = threadIdx.x;
    const int bid  = blockIdx.x;
    const int wave = tid >> 6, lane = tid & 63;

    const int slice = bid >> 4;               // out cols slice*16..slice*16+15
    const int usub  = bid & 15;               // t-partition g%16==usub
    const int e0 = slice * 16 + wave * 4;
    float4 w[4][4];
    #pragma unroll
    for (int r = 0; r < 4; ++r) {
        const float4* wr = (const float4*)(wv + (size_t)(e0 + r) * DM);
        #pragma unroll
        for (int jj = 0; jj < 4; ++jj) w[r][jj] = wr[jj * 64 + lane];
    }
    if (tid == 0) hits_n = 0;
    __syncthreads();
    #pragma unroll
    for (int k = 0; k < 4; ++k) {             // scan my 4 of 1024 g's
        const int m4 = tid + 256 * k;
        const int g = usub + (m4 << 4);
        const int s = idx[g];
        const int b2 = g >> 12;
        if (rep[(b2 << 12) + s] == (g & (TT - 1))) {
            const int pos = atomicAdd(&hits_n, 1);
            hits_g[pos] = g;
        }
    }
    __syncthreads();
    const int nh = hits_n;
    for (int h = 0; h < nh; ++h) {
        const int g  = hits_g[h];
        const int b2 = g >> 12;
        const int s  = idx[g];
        const int bs = (b2 << 12) + s;
        const float4* xr = (const float4*)(x + (size_t)bs * DM);
        float4 xv[4];
        #pragma unroll
        for (int jj = 0; jj < 4; ++jj) xv[jj] = xr[jj * 64 + lane];
        float s0 = 0.f, s1 = 0.f, s2 = 0.f, s3 = 0.f;
        #pragma unroll
        for (int jj = 0; jj < 4; ++jj) {
            s0 += dot4(w[0][jj], xv[jj]);
            s1 += dot4(w[1][jj], xv[jj]);
            s2 += dot4(w[2][jj], xv[jj]);
            s3 += dot4(w[3][jj], xv[jj]);
        }
        #pragma unroll
        for (int off = 32; off > 0; off >>= 1) {
            s0 += __shfl_down(s0, off);
            s1 += __shfl_down(s1, off);
            s2 += __shfl_down(s2, off);
            s3 += __shfl_down(s3, off);
        }
        if (lane == 0)
            *(float4*)(out + (size_t)g * DM + e0) = make_float4(s0, s1, s2, s3);
    }
}

// ---------- Kernel 4: broadcast representative rows (verbatim round-3/8,
//            passed). 4 rows per block, wave-per-row. ----------
__global__ __launch_bounds__(256) void gather_kernel(const int* __restrict__ idx,
                                                     const int* __restrict__ rep,
                                                     float* __restrict__ out) {
    const int tid = threadIdx.x, wave = tid >> 6, lane = tid & 63;
    const int bt = blockIdx.x * 4 + wave;
    const int b = bt >> 12, t = bt & (TT - 1);
    const int s = idx[bt];
    const int r = rep[b * TT + s];
    if (r == t) return;                       // wave-uniform
    const float4* src = (const float4*)(out + ((size_t)(b * TT + r)) * DM);
    float4* dst = (float4*)(out + (size_t)bt * DM);
    #pragma unroll
    for (int k = 0; k < 4; ++k) dst[k * 64 + lane] = src[k * 64 + lane];
}

extern "C" void kernel_launch(void* const* d_in, const int* in_sizes, int n_in,
                              void* d_out, int out_size, void* d_ws, size_t ws_size,
                              hipStream_t stream) {
    const float* x  = (const float*)d_in[0];
    const float* wq = (const float*)d_in[1];
    const float* wk = (const float*)d_in[2];
    const float* wv = (const float*)d_in[3];
    float* out = (float*)d_out;

    char* ws = (char*)d_ws;
    float* Q   = (float*)(ws);
    float* K   = (float*)(ws + 131072);
    int*   idx = (int*)  (ws + 262144);
    int*   rep = (int*)  (ws + 327680);

    qk_kernel<<<BT / 16, 256, 0, stream>>>(x, wq, wk, Q, K, rep);
    argmax_kernel<<<BB * 256, 256, 0, stream>>>(Q, K, idx, rep);
    vrow_kernel<<<1024, 256, 0, stream>>>(x, wv, idx, rep, out);
    gather_kernel<<<BT / 4, 256, 0, stream>>>(idx, rep, out);
}

// Round 10
// 212.951 us; speedup vs baseline: 1.1175x; 1.0160x over previous
//
#include <hip/hip_runtime.h>
#include <math.h>

#define TT 4096
#define DM 1024
#define BB 4
#define BT (BB * TT)
#define SENTINEL 0x7fffffff

// ws layout (bytes):
//   Q    : float[BT*2]  @ 0        (131072)
//   K    : float[BT*2]  @ 131072   (131072)  (interleaved k0,k1 pairs)
//   idx  : int[BT]      @ 262144   (65536)
//   rep  : int[BT]      @ 327680   (65536)
//   list : int[BT]      @ 393216   (65536)
//   cnt  : int          @ 458752   (4)

__device__ __forceinline__ float dot4(const float4 a, const float4 b) {
    return a.x * b.x + a.y * b.y + a.z * b.z + a.w * b.w;
}

// ---------- Kernel 1: Q,K projection. 8 rows per block (wave does 2 rows),
//            weights staged once in LDS. Also init rep[] and cnt. ----------
__global__ __launch_bounds__(256) void qk_kernel(const float* __restrict__ x,
                                                 const float* __restrict__ wq,
                                                 const float* __restrict__ wk,
                                                 float* __restrict__ Q,
                                                 float* __restrict__ K,
                                                 int* __restrict__ rep,
                                                 int* __restrict__ cnt) {
    __shared__ float4 ws[4][256];   // wq row0, wq row1, wk row0, wk row1 (16 KB)
    const int tid = threadIdx.x;
    const int row0 = blockIdx.x * 8;

    ws[0][tid] = ((const float4*)(wq))[tid];
    ws[1][tid] = ((const float4*)(wq + DM))[tid];
    ws[2][tid] = ((const float4*)(wk))[tid];
    ws[3][tid] = ((const float4*)(wk + DM))[tid];

    if (tid < 8) rep[row0 + tid] = SENTINEL;
    if (blockIdx.x == 0 && tid == 8) cnt[0] = 0;
    __syncthreads();

    const int wave = tid >> 6, lane = tid & 63;

    #pragma unroll
    for (int g = 0; g < 2; ++g) {
        const int row = row0 + g * 4 + wave;
        const float4* xr = (const float4*)(x + (size_t)row * DM);

        float s0 = 0.f, s1 = 0.f, s2 = 0.f, s3 = 0.f;
        #pragma unroll
        for (int j = 0; j < 4; ++j) {
            const float4 xv = xr[j * 64 + lane];
            s0 += dot4(xv, ws[0][j * 64 + lane]);
            s1 += dot4(xv, ws[1][j * 64 + lane]);
            s2 += dot4(xv, ws[2][j * 64 + lane]);
            s3 += dot4(xv, ws[3][j * 64 + lane]);
        }
        #pragma unroll
        for (int off = 32; off > 0; off >>= 1) {
            s0 += __shfl_down(s0, off);
            s1 += __shfl_down(s1, off);
            s2 += __shfl_down(s2, off);
            s3 += __shfl_down(s3, off);
        }
        if (lane == 0) {
            ((float2*)Q)[row] = make_float2(s0, s1);
            ((float2*)K)[row] = make_float2(s2, s3);
        }
    }
}

// ---------- Kernel 2: causal argmax. Paired tiles (j, 1023-j) per block:
//            K prefix staged ONCE (small tile's prefix is a subset of big's),
//            float4 staging, constant compute per block. ----------
__global__ __launch_bounds__(256) void argmax_kernel(const float* __restrict__ Q,
                                                     const float* __restrict__ K,
                                                     int* __restrict__ idx,
                                                     int* __restrict__ rep,
                                                     int* __restrict__ list,
                                                     int* __restrict__ cnt) {
    __shared__ float2 ks[TT];   // 32 KB
    const int b = blockIdx.x >> 9;
    const int j = blockIdx.x & 511;           // pair: tg = 1023-j (big), j (small)
    const int tid = threadIdx.x;

    // stage the BIG tile's prefix once; nfill = (1023-j)*4+4 float2s
    const int nfill4 = (((1023 - j) * 4 + 4) >> 1);   // float4 count
    const float4* kb4 = (const float4*)(K + (size_t)b * TT * 2);
    float4* ks4 = (float4*)ks;
    for (int i = tid; i < nfill4; i += 256) ks4[i] = kb4[i];
    __syncthreads();

    const int wave = tid >> 6, lane = tid & 63;
    const float4* kp = (const float4*)ks;   // pair p -> points 2p, 2p+1

    #pragma unroll
    for (int u = 0; u < 2; ++u) {
        const int tg = u ? j : (1023 - j);
        const int t = tg * 4 + wave;
        const float2 q = ((const float2*)Q)[b * TT + t];

        float best = -INFINITY;
        int bi = SENTINEL;
        int p = lane;
        // main: both pairs fully in range; in-lane ascending s order + strict '>'
        while (2 * (p + 64) + 1 <= t) {
            const float4 a = kp[p];
            const float4 c = kp[p + 64];
            const float c0 = q.x * a.x + q.y * a.y;
            const float c1 = q.x * a.z + q.y * a.w;
            const float c2 = q.x * c.x + q.y * c.y;
            const float c3 = q.x * c.z + q.y * c.w;
            if (c0 > best) { best = c0; bi = 2 * p; }
            if (c1 > best) { best = c1; bi = 2 * p + 1; }
            if (c2 > best) { best = c2; bi = 2 * (p + 64); }
            if (c3 > best) { best = c3; bi = 2 * (p + 64) + 1; }
            p += 128;
        }
        while (2 * p <= t) {
            const float4 a = kp[p];
            const float c0 = q.x * a.x + q.y * a.y;
            if (c0 > best) { best = c0; bi = 2 * p; }
            if (2 * p + 1 <= t) {
                const float c1 = q.x * a.z + q.y * a.w;
                if (c1 > best) { best = c1; bi = 2 * p + 1; }
            }
            p += 64;
        }
        // cross-lane argmax, first-occurrence tie-break
        #pragma unroll
        for (int off = 32; off > 0; off >>= 1) {
            const float ov = __shfl_down(best, off);
            const int   oi = __shfl_down(bi, off);
            if (ov > best || (ov == best && oi < bi)) { best = ov; bi = oi; }
        }
        if (lane == 0) {
            idx[b * TT + t] = bi;
            const int old = atomicMin(&rep[b * TT + bi], t);
            if (old == SENTINEL) {
                const int pp = atomicAdd(cnt, 1);
                list[pp] = b * TT + bi;
            }
        }
        // no __syncthreads needed: LDS is read-only across both tiles
    }
}

// ---------- Kernel 3: V-rows. 64 slices x 16 cols; wave owns 4 cols in 64 VGPRs;
//            16-way usub split over unique rows. ----------
__global__ __launch_bounds__(256) void vrow_kernel(const float* __restrict__ x,
                                                   const float* __restrict__ wv,
                                                   const int* __restrict__ rep,
                                                   const int* __restrict__ list,
                                                   const int* __restrict__ cnt,
                                                   float* __restrict__ out) {
    const int tid = threadIdx.x, wave = tid >> 6, lane = tid & 63;
    const int slice = blockIdx.x >> 4;     // [0,64): W_V rows slice*16 .. slice*16+15
    const int usub  = blockIdx.x & 15;
    const int e0 = slice * 16 + wave * 4;  // 4 output elements owned by this wave

    float4 w[4][4];
    #pragma unroll
    for (int r = 0; r < 4; ++r) {
        const float4* wr = (const float4*)(wv + (size_t)(e0 + r) * DM);
        #pragma unroll
        for (int j = 0; j < 4; ++j) w[r][j] = wr[j * 64 + lane];
    }

    const int n = cnt[0];
    for (int li = usub; li < n; li += 16) {
        const int bs = list[li];
        const int b  = bs >> 12;
        const int r  = rep[bs];
        const float4* xr = (const float4*)(x + (size_t)bs * DM);
        float4 xv[4];
        #pragma unroll
        for (int j = 0; j < 4; ++j) xv[j] = xr[j * 64 + lane];

        float s0 = 0.f, s1 = 0.f, s2 = 0.f, s3 = 0.f;
        #pragma unroll
        for (int j = 0; j < 4; ++j) {
            s0 += dot4(w[0][j], xv[j]);
            s1 += dot4(w[1][j], xv[j]);
            s2 += dot4(w[2][j], xv[j]);
            s3 += dot4(w[3][j], xv[j]);
        }
        #pragma unroll
        for (int off = 32; off > 0; off >>= 1) {
            s0 += __shfl_down(s0, off);
            s1 += __shfl_down(s1, off);
            s2 += __shfl_down(s2, off);
            s3 += __shfl_down(s3, off);
        }
        if (lane == 0)
            *(float4*)(out + ((size_t)(b * TT + r)) * DM + e0) = make_float4(s0, s1, s2, s3);
    }
}

// ---------- Kernel 4: broadcast representative rows to all t.
//            4 rows per block (wave-per-row) to amortize the idx->rep chain. ----------
__global__ __launch_bounds__(256) void gather_kernel(const int* __restrict__ idx,
                                                     const int* __restrict__ rep,
                                                     float* __restrict__ out) {
    const int tid = threadIdx.x, wave = tid >> 6, lane = tid & 63;
    const int bt = blockIdx.x * 4 + wave;
    const int b = bt >> 12, t = bt & (TT - 1);
    const int s = idx[bt];
    const int r = rep[b * TT + s];
    if (r == t) return;                       // wave-uniform
    const float4* src = (const float4*)(out + ((size_t)(b * TT + r)) * DM);
    float4* dst = (float4*)(out + (size_t)bt * DM);
    #pragma unroll
    for (int k = 0; k < 4; ++k) dst[k * 64 + lane] = src[k * 64 + lane];
}

extern "C" void kernel_launch(void* const* d_in, const int* in_sizes, int n_in,
                              void* d_out, int out_size, void* d_ws, size_t ws_size,
                              hipStream_t stream) {
    const float* x  = (const float*)d_in[0];
    const float* wq = (const float*)d_in[1];
    const float* wk = (const float*)d_in[2];
    const float* wv = (const float*)d_in[3];
    float* out = (float*)d_out;

    char* ws = (char*)d_ws;
    float* Q    = (float*)(ws);
    float* K    = (float*)(ws + 131072);
    int*   idx  = (int*)  (ws + 262144);
    int*   rep  = (int*)  (ws + 327680);
    int*   list = (int*)  (ws + 393216);
    int*   cnt  = (int*)  (ws + 458752);

    qk_kernel<<<BT / 8, 256, 0, stream>>>(x, wq, wk, Q, K, rep, cnt);
    argmax_kernel<<<BB * 512, 256, 0, stream>>>(Q, K, idx, rep, list, cnt);
    vrow_kernel<<<1024, 256, 0, stream>>>(x, wv, rep, list, cnt, out);
    gather_kernel<<<BT / 4, 256, 0, stream>>>(idx, rep, out);
}